// Round 6
// baseline (1223.257 us; speedup 1.0000x reference)
//
#include <hip/hip_runtime.h>
#include <hip/hip_bf16.h>

// Problem constants (from reference): N=262144, NS=8, C=32, S=8 -> C/S=4
#define NPTS   262144
#define NSAMP  8
#define NPAIR  (NPTS * NSAMP)           // 2097152
#define EPSV   1e-5f
#define INVCNT (1.0f / (float)NPAIR)
#define GSTAT  2048                      // pair-kernel grid: 8 blocks/CU
#define PPB    (NPAIR / GSTAT)           // 1024 pairs per block

typedef __hip_bfloat16 bf16;

template <typename T> __device__ __forceinline__ float cvt(T v);
template <> __device__ __forceinline__ float cvt<float>(float v) { return v; }
template <> __device__ __forceinline__ float cvt<bf16>(bf16 v) { return __bfloat162float(v); }

template <typename T> __device__ __forceinline__ T f2t(float v);
template <> __device__ __forceinline__ float f2t<float>(float v) { return v; }
template <> __device__ __forceinline__ bf16  f2t<bf16>(float v)  { return __float2bfloat16(v); }

// ---------------------------------------------------------------------------
// Detector: bf16 inputs (flag=0) vs fp32 inputs (flag=1).
// ---------------------------------------------------------------------------
__global__ void k_detect(const unsigned int* __restrict__ xw, int* __restrict__ flag)
{
    if (threadIdx.x == 0 && blockIdx.x == 0) {
        int cnt = 0;
        for (int i = 0; i < 256; ++i) {
            const unsigned int w = xw[i];
            const unsigned int e = (w >> 7) & 0xFF;   // exponent of low bf16
            if (e >= 110 && e <= 132) ++cnt;
        }
        flag[0] = (cnt >= 128) ? 0 : 1;
    }
}

// ===========================================================================
// K1: q,k,v = x @ W.T + b (fp32 out). thread=(point-in-chunk, c), 128 pts/blk
// ===========================================================================
template <typename T>
__device__ __forceinline__ void qkv_impl(
    const T* __restrict__ x,
    const T* __restrict__ Wq, const T* __restrict__ bq,
    const T* __restrict__ Wk, const T* __restrict__ bk,
    const T* __restrict__ Wv, const T* __restrict__ bv,
    float* __restrict__ q, float* __restrict__ k, float* __restrict__ v,
    float (*Wt)[32][32], float (*xs)[32])
{
    const int t = threadIdx.x;
    for (int e = t; e < 1024; e += 256) {
        const int c = e >> 5, j = e & 31;
        Wt[0][j][c] = cvt<T>(Wq[e]);
        Wt[1][j][c] = cvt<T>(Wk[e]);
        Wt[2][j][c] = cvt<T>(Wv[e]);
    }
    __syncthreads();
    const int c = t & 31, pi = t >> 5;
    const float bqv = cvt<T>(bq[c]), bkv = cvt<T>(bk[c]), bvv = cvt<T>(bv[c]);
    const int base0 = blockIdx.x * 128;
    for (int it = 0; it < 16; ++it) {
        const int base = base0 + it * 8;
        __syncthreads();
        xs[t >> 5][t & 31] = cvt<T>(x[(size_t)base * 32 + t]);
        __syncthreads();
        float aq = bqv, ak = bkv, av = bvv;
#pragma unroll
        for (int j = 0; j < 32; ++j) {
            const float xv = xs[pi][j];
            aq += Wt[0][j][c] * xv;
            ak += Wt[1][j][c] * xv;
            av += Wt[2][j][c] * xv;
        }
        const size_t o = (size_t)(base + pi) * 32 + c;
        q[o] = aq; k[o] = ak; v[o] = av;
    }
}

__global__ __launch_bounds__(256) void k_qkv(
    const void* x, const void* Wq, const void* bq, const void* Wk, const void* bk,
    const void* Wv, const void* bv,
    float* q, float* k, float* v, const int* __restrict__ flag)
{
    __shared__ float Wt[3][32][32];
    __shared__ float xs[8][32];
    if (flag[0] == 0)
        qkv_impl<bf16>((const bf16*)x, (const bf16*)Wq, (const bf16*)bq, (const bf16*)Wk,
                       (const bf16*)bk, (const bf16*)Wv, (const bf16*)bv, q, k, v, Wt, xs);
    else
        qkv_impl<float>((const float*)x, (const float*)Wq, (const float*)bq, (const float*)Wk,
                        (const float*)bk, (const float*)Wv, (const float*)bv, q, k, v, Wt, xs);
}

// ===========================================================================
// K2: pr1 = (p[idx]-p) @ Wp1.T + bp1 (store), BN1 partials (3 ch, pad 8)
// ===========================================================================
template <typename T>
__device__ __forceinline__ void pr1_impl(
    const T* __restrict__ p, const int* __restrict__ idx,
    const T* __restrict__ Wp1, const T* __restrict__ bp1,
    float* __restrict__ pr1, float* __restrict__ P1, float (*red)[16])
{
    float W[3][3], B[3];
#pragma unroll
    for (int a = 0; a < 3; ++a) {
        B[a] = cvt<T>(bp1[a]);
#pragma unroll
        for (int d = 0; d < 3; ++d) W[a][d] = cvt<T>(Wp1[a * 3 + d]);
    }
    const int t = threadIdx.x;
    const int base = blockIdx.x * PPB;
    float s[3] = {0.f, 0.f, 0.f}, ss[3] = {0.f, 0.f, 0.f};
    for (int it = 0; it < PPB; it += 256) {
        const int pid = base + it + t;
        const int i = pid >> 3;
        const int nj = idx[pid];
        const float d0 = cvt<T>(p[nj * 3 + 0]) - cvt<T>(p[i * 3 + 0]);
        const float d1 = cvt<T>(p[nj * 3 + 1]) - cvt<T>(p[i * 3 + 1]);
        const float d2 = cvt<T>(p[nj * 3 + 2]) - cvt<T>(p[i * 3 + 2]);
#pragma unroll
        for (int a = 0; a < 3; ++a) {
            const float r = W[a][0] * d0 + W[a][1] * d1 + W[a][2] * d2 + B[a];
            pr1[(size_t)pid * 3 + a] = r;
            s[a] += r; ss[a] += r * r;
        }
    }
#pragma unroll
    for (int o = 32; o > 0; o >>= 1) {
#pragma unroll
        for (int a = 0; a < 3; ++a) { s[a] += __shfl_down(s[a], o); ss[a] += __shfl_down(ss[a], o); }
    }
    const int wid = t >> 6, lane = t & 63;
    if (lane == 0) {
#pragma unroll
        for (int u = 0; u < 16; ++u) red[wid][u] = 0.f;
#pragma unroll
        for (int a = 0; a < 3; ++a) { red[wid][a] = s[a]; red[wid][8 + a] = ss[a]; }
    }
    __syncthreads();
    if (t < 16) P1[blockIdx.x * 16 + t] = red[0][t] + red[1][t] + red[2][t] + red[3][t];
}

__global__ __launch_bounds__(256) void k_pr1(
    const void* p, const int* __restrict__ idx, const void* Wp1, const void* bp1,
    float* pr1, float* P1, const int* __restrict__ flag)
{
    __shared__ float red[4][16];
    if (flag[0] == 0)
        pr1_impl<bf16>((const bf16*)p, idx, (const bf16*)Wp1, (const bf16*)bp1, pr1, P1, red);
    else
        pr1_impl<float>((const float*)p, idx, (const float*)Wp1, (const float*)bp1, pr1, P1, red);
}

// ===========================================================================
// Finalize: reduce GSTAT partial rows (2*NP cols) -> coef a/c. 1024 threads.
// ===========================================================================
template <typename T, int NC_, int NP_>
__device__ __forceinline__ void fin_impl(
    const float* __restrict__ P, const int nblocks,
    const T* __restrict__ g, const T* __restrict__ b,
    float* __restrict__ A, float* __restrict__ Cc, float* red)
{
    constexpr int COLS = 2 * NP_;
    constexpr int GRP  = 1024 / COLS;
    const int t = threadIdx.x;
    const int c = t % COLS;
    const int gi = t / COLS;
    float acc = 0.f;
    for (int r = gi; r < nblocks; r += GRP) acc += P[r * COLS + c];
    red[t] = acc;
    __syncthreads();
#pragma unroll
    for (int s = GRP >> 1; s > 0; s >>= 1) {
        if (gi < s) red[t] += red[t + s * COLS];
        __syncthreads();
    }
    if (t < NC_) {
        const float m = red[t] * INVCNT;
        const float var = red[NP_ + t] * INVCNT - m * m;
        const float a = cvt<T>(g[t]) * rsqrtf(var + EPSV);
        A[t] = a;
        Cc[t] = cvt<T>(b[t]) - a * m;
    }
}

template <int NC_, int NP_>
__global__ __launch_bounds__(1024) void k_fin(
    const float* P, const int nblocks, const void* g, const void* b,
    float* A, float* Cc, const int* __restrict__ flag)
{
    __shared__ float red[1024];
    if (flag[0] == 0)
        fin_impl<bf16, NC_, NP_>(P, nblocks, (const bf16*)g, (const bf16*)b, A, Cc, red);
    else
        fin_impl<float, NC_, NP_>(P, nblocks, (const float*)g, (const float*)b, A, Cc, red);
}

// ===========================================================================
// K4: BN2 partials over w_pre = k[idx] - q + relu(bn1(pr1)) @ Wp2.T + bp2
// c = t&31 channel-parallel; 4-way ILP batches.
// ===========================================================================
template <typename T>
__device__ __forceinline__ void bn2_impl(
    const int* __restrict__ idx, const float* __restrict__ pr1,
    const float* __restrict__ q, const float* __restrict__ k,
    const T* __restrict__ Wp2, const T* __restrict__ bp2,
    const float* __restrict__ coef, float* __restrict__ P2, float (*red)[64])
{
    const int t = threadIdx.x;
    const int c = t & 31;
    const int sub = t >> 5;
    const float a10 = coef[0], a11 = coef[1], a12 = coef[2];
    const float c10 = coef[8], c11 = coef[9], c12 = coef[10];
    const float w0 = cvt<T>(Wp2[c * 3 + 0]), w1 = cvt<T>(Wp2[c * 3 + 1]), w2 = cvt<T>(Wp2[c * 3 + 2]);
    const float bb = cvt<T>(bp2[c]);
    float s = 0.f, ss = 0.f;
    const int base = blockIdx.x * PPB;
    for (int it = 0; it < PPB; it += 32) {
        int pids[4], njs[4];
#pragma unroll
        for (int u = 0; u < 4; ++u) pids[u] = base + it + u * 8 + sub;
#pragma unroll
        for (int u = 0; u < 4; ++u) njs[u] = idx[pids[u]];
        float h[4][3];
#pragma unroll
        for (int u = 0; u < 4; ++u) {
            h[u][0] = fmaxf(a10 * pr1[(size_t)pids[u] * 3 + 0] + c10, 0.f);
            h[u][1] = fmaxf(a11 * pr1[(size_t)pids[u] * 3 + 1] + c11, 0.f);
            h[u][2] = fmaxf(a12 * pr1[(size_t)pids[u] * 3 + 2] + c12, 0.f);
        }
        float kv[4], qv[4];
#pragma unroll
        for (int u = 0; u < 4; ++u) {
            kv[u] = k[(size_t)njs[u] * 32 + c];
            qv[u] = q[(size_t)(pids[u] >> 3) * 32 + c];
        }
#pragma unroll
        for (int u = 0; u < 4; ++u) {
            const float pr2 = w0 * h[u][0] + w1 * h[u][1] + w2 * h[u][2] + bb;
            const float wp = kv[u] - qv[u] + pr2;
            s += wp; ss += wp * wp;
        }
    }
    s += __shfl_down(s, 32); ss += __shfl_down(ss, 32);
    const int wid = t >> 6, lane = t & 63;
    if (lane < 32) { red[wid][lane] = s; red[wid][32 + lane] = ss; }
    __syncthreads();
    if (t < 64) P2[blockIdx.x * 64 + t] = red[0][t] + red[1][t] + red[2][t] + red[3][t];
}

__global__ __launch_bounds__(256) void k_bn2stat(
    const int* __restrict__ idx, const float* pr1, const float* q, const float* k,
    const void* Wp2, const void* bp2, const float* coef, float* P2,
    const int* __restrict__ flag)
{
    __shared__ float red[4][64];
    if (flag[0] == 0)
        bn2_impl<bf16>(idx, pr1, q, k, (const bf16*)Wp2, (const bf16*)bp2, coef, P2, red);
    else
        bn2_impl<float>(idx, pr1, q, k, (const float*)Wp2, (const float*)bp2, coef, P2, red);
}

// ===========================================================================
// K6: w1 = relu(bn2(w_pre)) @ Ww1.T + bww1 (store), BN3 partials (4 ch)
// Thread-per-pair; rows loaded as 8x float4 (16 loads in flight);
// __launch_bounds__(256,4) caps VGPR at 128 (R5: 204 VGPR -> 10% occupancy).
// ===========================================================================
struct ShW1 {
    float Wp2c[32][3];
    float bp2[32];
    float W1[4][32];
    float b1[4];
    float a2[32];
    float c2[32];
    float red[4][8];
};

template <typename T>
__device__ __forceinline__ void w1_impl(
    const int* __restrict__ idx, const float* __restrict__ pr1,
    const float* __restrict__ q, const float* __restrict__ k,
    const T* __restrict__ Wp2, const T* __restrict__ bp2,
    const T* __restrict__ Ww1, const T* __restrict__ bww1,
    const float* __restrict__ coef, float* __restrict__ w1out, float* __restrict__ P3,
    ShW1* sh)
{
    const int t = threadIdx.x;
    if (t < 32) {
        sh->Wp2c[t][0] = cvt<T>(Wp2[t * 3 + 0]);
        sh->Wp2c[t][1] = cvt<T>(Wp2[t * 3 + 1]);
        sh->Wp2c[t][2] = cvt<T>(Wp2[t * 3 + 2]);
        sh->bp2[t] = cvt<T>(bp2[t]);
        sh->a2[t] = coef[16 + t];
        sh->c2[t] = coef[48 + t];
    }
    if (t < 4) sh->b1[t] = cvt<T>(bww1[t]);
    if (t < 128) sh->W1[t >> 5][t & 31] = cvt<T>(Ww1[t]);
    __syncthreads();
    const float a10 = coef[0], a11 = coef[1], a12 = coef[2];
    const float c10 = coef[8], c11 = coef[9], c12 = coef[10];
    float s[4] = {0.f, 0.f, 0.f, 0.f}, ss[4] = {0.f, 0.f, 0.f, 0.f};
    const int base = blockIdx.x * PPB;
    for (int it = 0; it < PPB; it += 256) {
        const int pid = base + it + t;
        const int i = pid >> 3;
        const int nj = idx[pid];
        const float4* k4 = (const float4*)(k + (size_t)nj * 32);
        const float4* q4 = (const float4*)(q + (size_t)i * 32);
        float4 kk[8], qq[8];
#pragma unroll
        for (int u = 0; u < 8; ++u) kk[u] = k4[u];
#pragma unroll
        for (int u = 0; u < 8; ++u) qq[u] = q4[u];
        const float h0 = fmaxf(a10 * pr1[(size_t)pid * 3 + 0] + c10, 0.f);
        const float h1 = fmaxf(a11 * pr1[(size_t)pid * 3 + 1] + c11, 0.f);
        const float h2 = fmaxf(a12 * pr1[(size_t)pid * 3 + 2] + c12, 0.f);
        float acc0 = sh->b1[0], acc1 = sh->b1[1], acc2 = sh->b1[2], acc3 = sh->b1[3];
#pragma unroll
        for (int u = 0; u < 8; ++u) {
            const float kd[4] = {kk[u].x - qq[u].x, kk[u].y - qq[u].y,
                                 kk[u].z - qq[u].z, kk[u].w - qq[u].w};
#pragma unroll
            for (int e = 0; e < 4; ++e) {
                const int cc = u * 4 + e;
                const float pr2 = sh->Wp2c[cc][0] * h0 + sh->Wp2c[cc][1] * h1
                                + sh->Wp2c[cc][2] * h2 + sh->bp2[cc];
                const float wp = kd[e] + pr2;
                const float hh = fmaxf(sh->a2[cc] * wp + sh->c2[cc], 0.f);
                acc0 += sh->W1[0][cc] * hh;
                acc1 += sh->W1[1][cc] * hh;
                acc2 += sh->W1[2][cc] * hh;
                acc3 += sh->W1[3][cc] * hh;
            }
        }
        float* wr = w1out + (size_t)pid * 4;
        wr[0] = acc0; wr[1] = acc1; wr[2] = acc2; wr[3] = acc3;
        s[0] += acc0; ss[0] += acc0 * acc0;
        s[1] += acc1; ss[1] += acc1 * acc1;
        s[2] += acc2; ss[2] += acc2 * acc2;
        s[3] += acc3; ss[3] += acc3 * acc3;
    }
#pragma unroll
    for (int o = 32; o > 0; o >>= 1) {
#pragma unroll
        for (int u = 0; u < 4; ++u) { s[u] += __shfl_down(s[u], o); ss[u] += __shfl_down(ss[u], o); }
    }
    const int wid = t >> 6, lane = t & 63;
    if (lane == 0) {
#pragma unroll
        for (int u = 0; u < 4; ++u) { sh->red[wid][u] = s[u]; sh->red[wid][4 + u] = ss[u]; }
    }
    __syncthreads();
    if (t < 8) P3[blockIdx.x * 8 + t] = sh->red[0][t] + sh->red[1][t] + sh->red[2][t] + sh->red[3][t];
}

__global__ __launch_bounds__(256, 4) void k_w1(
    const int* __restrict__ idx, const float* pr1, const float* q, const float* k,
    const void* Wp2, const void* bp2, const void* Ww1, const void* bww1,
    const float* coef, float* w1out, float* P3, const int* __restrict__ flag)
{
    __shared__ ShW1 sh;
    if (flag[0] == 0)
        w1_impl<bf16>(idx, pr1, q, k, (const bf16*)Wp2, (const bf16*)bp2,
                      (const bf16*)Ww1, (const bf16*)bww1, coef, w1out, P3, &sh);
    else
        w1_impl<float>(idx, pr1, q, k, (const float*)Wp2, (const float*)bp2,
                       (const float*)Ww1, (const float*)bww1, coef, w1out, P3, &sh);
}

// ===========================================================================
// K8: logits = relu(bn3(w1)) @ Ww2.T + bww2; softmax over ns;
//     out[i,c] = sum_j (v[idx]+pr2) * wsoft[j, c&3].  128 points per block.
// Batched idx loads -> 8 v-row gathers in flight.
// ===========================================================================
template <typename T>
__device__ __forceinline__ void out_impl(
    const int* __restrict__ idx, const float* __restrict__ pr1,
    const float* __restrict__ v, const float* __restrict__ w1in,
    const T* __restrict__ Wp2, const T* __restrict__ bp2,
    const T* __restrict__ Ww2, const T* __restrict__ bww2,
    const float* __restrict__ coef, T* __restrict__ out)
{
    const int t = threadIdx.x;
    const int c = t & 31, pi = t >> 5;
    const float a10 = coef[0], a11 = coef[1], a12 = coef[2];
    const float c10 = coef[8], c11 = coef[9], c12 = coef[10];
    const float wA = cvt<T>(Wp2[c * 3 + 0]), wB = cvt<T>(Wp2[c * 3 + 1]), wC = cvt<T>(Wp2[c * 3 + 2]);
    const float bb = cvt<T>(bp2[c]);
    const int tq = c & 3;
    float a3[4], c3[4], W2r[4];
#pragma unroll
    for (int u = 0; u < 4; ++u) {
        a3[u] = coef[80 + u]; c3[u] = coef[88 + u];
        W2r[u] = cvt<T>(Ww2[tq * 4 + u]);
    }
    const float b2r = cvt<T>(bww2[tq]);
    const int base0 = blockIdx.x * 128;
    for (int it = 0; it < 16; ++it) {
        const int i = base0 + it * 8 + pi;
        int njs[8];
#pragma unroll
        for (int j = 0; j < 8; ++j) njs[j] = idx[(size_t)i * 8 + j];
        float vv[8];
#pragma unroll
        for (int j = 0; j < 8; ++j) vv[j] = v[(size_t)njs[j] * 32 + c];
        float lg[8];
#pragma unroll
        for (int j = 0; j < 8; ++j) {
            const float* wr = w1in + ((size_t)i * 8 + j) * 4;
            float l = b2r;
#pragma unroll
            for (int u = 0; u < 4; ++u) l += W2r[u] * fmaxf(a3[u] * wr[u] + c3[u], 0.f);
            lg[j] = l;
        }
        float h[8][3];
#pragma unroll
        for (int j = 0; j < 8; ++j) {
            const size_t pb = ((size_t)i * 8 + j) * 3;
            h[j][0] = fmaxf(a10 * pr1[pb + 0] + c10, 0.f);
            h[j][1] = fmaxf(a11 * pr1[pb + 1] + c11, 0.f);
            h[j][2] = fmaxf(a12 * pr1[pb + 2] + c12, 0.f);
        }
        float m = lg[0];
#pragma unroll
        for (int j = 1; j < 8; ++j) m = fmaxf(m, lg[j]);
        float sum = 0.f;
#pragma unroll
        for (int j = 0; j < 8; ++j) { lg[j] = __expf(lg[j] - m); sum += lg[j]; }
        const float inv = 1.f / sum;
        float acc = 0.f;
#pragma unroll
        for (int j = 0; j < 8; ++j) {
            const float pr2 = wA * h[j][0] + wB * h[j][1] + wC * h[j][2] + bb;
            acc += (vv[j] + pr2) * (lg[j] * inv);
        }
        out[(size_t)i * 32 + c] = f2t<T>(acc);
    }
}

__global__ __launch_bounds__(256, 4) void k_out(
    const int* __restrict__ idx, const float* pr1, const float* v, const float* w1in,
    const void* Wp2, const void* bp2, const void* Ww2, const void* bww2,
    const float* coef, void* out, const int* __restrict__ flag)
{
    if (flag[0] == 0)
        out_impl<bf16>(idx, pr1, v, w1in, (const bf16*)Wp2, (const bf16*)bp2,
                       (const bf16*)Ww2, (const bf16*)bww2, coef, (bf16*)out);
    else
        out_impl<float>(idx, pr1, v, w1in, (const float*)Wp2, (const float*)bp2,
                        (const float*)Ww2, (const float*)bww2, coef, (float*)out);
}

// ---------------------------------------------------------------------------
extern "C" void kernel_launch(void* const* d_in, const int* in_sizes, int n_in,
                              void* d_out, int out_size, void* d_ws, size_t ws_size,
                              hipStream_t stream)
{
    const void* p    = d_in[0];
    const void* x    = d_in[1];
    const int*  idx  = (const int*)d_in[2];
    const void* Wq   = d_in[3];
    const void* bq   = d_in[4];
    const void* Wk   = d_in[5];
    const void* bk   = d_in[6];
    const void* Wv   = d_in[7];
    const void* bv   = d_in[8];
    const void* Wp1  = d_in[9];
    const void* bp1  = d_in[10];
    const void* gp   = d_in[11];
    const void* bp   = d_in[12];
    const void* Wp2  = d_in[13];
    const void* bp2  = d_in[14];
    const void* gw1  = d_in[15];
    const void* bw1  = d_in[16];
    const void* Ww1  = d_in[17];
    const void* bww1 = d_in[18];
    const void* gw2  = d_in[19];
    const void* bw2  = d_in[20];
    const void* Ww2  = d_in[21];
    const void* bww2 = d_in[22];

    float* ws = (float*)d_ws;
    int* flag = (int*)ws;                     // ws[0]
    // ws layout: [0] flag (+pad), [16..112) coef, [128..) partials, big arrays after 262144
    float* coef = ws + 16;                    // 96 floats
    float* P1   = ws + 128;                   // GSTAT*16
    float* P2   = P1 + GSTAT * 16;            // GSTAT*64
    float* P3   = P2 + GSTAT * 64;            // GSTAT*8
    float* q    = ws + 262144;                // NPTS*32
    float* k    = q  + (size_t)NPTS * 32;     // NPTS*32
    float* v    = k  + (size_t)NPTS * 32;     // NPTS*32
    float* pr1  = v  + (size_t)NPTS * 32;     // NPAIR*3
    float* w1   = pr1 + (size_t)NPAIR * 3;    // NPAIR*4   (total ~160 MB)

    k_detect<<<1, 64, 0, stream>>>((const unsigned int*)x, flag);
    k_qkv<<<2048, 256, 0, stream>>>(x, Wq, bq, Wk, bk, Wv, bv, q, k, v, flag);
    k_pr1<<<GSTAT, 256, 0, stream>>>(p, idx, Wp1, bp1, pr1, P1, flag);
    k_fin<3, 8><<<1, 1024, 0, stream>>>(P1, GSTAT, gp, bp, coef + 0, coef + 8, flag);
    k_bn2stat<<<GSTAT, 256, 0, stream>>>(idx, pr1, q, k, Wp2, bp2, coef, P2, flag);
    k_fin<32, 32><<<1, 1024, 0, stream>>>(P2, GSTAT, gw1, bw1, coef + 16, coef + 48, flag);
    k_w1<<<GSTAT, 256, 0, stream>>>(idx, pr1, q, k, Wp2, bp2, Ww1, bww1, coef, w1, P3, flag);
    k_fin<4, 4><<<1, 1024, 0, stream>>>(P3, GSTAT, gw2, bw2, coef + 80, coef + 88, flag);
    k_out<<<2048, 256, 0, stream>>>(idx, pr1, v, w1, Wp2, bp2, Ww2, bww2, coef, d_out, flag);
}

// Round 7
// 1217.304 us; speedup vs baseline: 1.0049x; 1.0049x over previous
//
#include <hip/hip_runtime.h>
#include <hip/hip_bf16.h>

// Problem constants (from reference): N=262144, NS=8, C=32, S=8 -> C/S=4
#define NPTS   262144
#define NSAMP  8
#define NPAIR  (NPTS * NSAMP)           // 2097152
#define EPSV   1e-5f
#define INVCNT (1.0f / (float)NPAIR)
#define GSTAT  2048                      // pair-kernel grid: 8 blocks/CU
#define PPB    (NPAIR / GSTAT)           // 1024 pairs per block

typedef __hip_bfloat16 bf16;

template <typename T> __device__ __forceinline__ float cvt(T v);
template <> __device__ __forceinline__ float cvt<float>(float v) { return v; }
template <> __device__ __forceinline__ float cvt<bf16>(bf16 v) { return __bfloat162float(v); }

template <typename T> __device__ __forceinline__ T f2t(float v);
template <> __device__ __forceinline__ float f2t<float>(float v) { return v; }
template <> __device__ __forceinline__ bf16  f2t<bf16>(float v)  { return __float2bfloat16(v); }

// ---------------------------------------------------------------------------
// Detector: bf16 inputs (flag=0) vs fp32 inputs (flag=1).
// ---------------------------------------------------------------------------
__global__ void k_detect(const unsigned int* __restrict__ xw, int* __restrict__ flag)
{
    if (threadIdx.x == 0 && blockIdx.x == 0) {
        int cnt = 0;
        for (int i = 0; i < 256; ++i) {
            const unsigned int w = xw[i];
            const unsigned int e = (w >> 7) & 0xFF;   // exponent of low bf16
            if (e >= 110 && e <= 132) ++cnt;
        }
        flag[0] = (cnt >= 128) ? 0 : 1;
    }
}

// ===========================================================================
// K1: q,k,v = x @ W.T + b (fp32 out). thread=(point-in-chunk, c), 128 pts/blk
// ===========================================================================
template <typename T>
__device__ __forceinline__ void qkv_impl(
    const T* __restrict__ x,
    const T* __restrict__ Wq, const T* __restrict__ bq,
    const T* __restrict__ Wk, const T* __restrict__ bk,
    const T* __restrict__ Wv, const T* __restrict__ bv,
    float* __restrict__ q, float* __restrict__ k, float* __restrict__ v,
    float (*Wt)[32][32], float (*xs)[32])
{
    const int t = threadIdx.x;
    for (int e = t; e < 1024; e += 256) {
        const int c = e >> 5, j = e & 31;
        Wt[0][j][c] = cvt<T>(Wq[e]);
        Wt[1][j][c] = cvt<T>(Wk[e]);
        Wt[2][j][c] = cvt<T>(Wv[e]);
    }
    __syncthreads();
    const int c = t & 31, pi = t >> 5;
    const float bqv = cvt<T>(bq[c]), bkv = cvt<T>(bk[c]), bvv = cvt<T>(bv[c]);
    const int base0 = blockIdx.x * 128;
    for (int it = 0; it < 16; ++it) {
        const int base = base0 + it * 8;
        __syncthreads();
        xs[t >> 5][t & 31] = cvt<T>(x[(size_t)base * 32 + t]);
        __syncthreads();
        float aq = bqv, ak = bkv, av = bvv;
#pragma unroll
        for (int j = 0; j < 32; ++j) {
            const float xv = xs[pi][j];
            aq += Wt[0][j][c] * xv;
            ak += Wt[1][j][c] * xv;
            av += Wt[2][j][c] * xv;
        }
        const size_t o = (size_t)(base + pi) * 32 + c;
        q[o] = aq; k[o] = ak; v[o] = av;
    }
}

__global__ __launch_bounds__(256) void k_qkv(
    const void* x, const void* Wq, const void* bq, const void* Wk, const void* bk,
    const void* Wv, const void* bv,
    float* q, float* k, float* v, const int* __restrict__ flag)
{
    __shared__ float Wt[3][32][32];
    __shared__ float xs[8][32];
    if (flag[0] == 0)
        qkv_impl<bf16>((const bf16*)x, (const bf16*)Wq, (const bf16*)bq, (const bf16*)Wk,
                       (const bf16*)bk, (const bf16*)Wv, (const bf16*)bv, q, k, v, Wt, xs);
    else
        qkv_impl<float>((const float*)x, (const float*)Wq, (const float*)bq, (const float*)Wk,
                        (const float*)bk, (const float*)Wv, (const float*)bv, q, k, v, Wt, xs);
}

// ===========================================================================
// K2: pr1 = (p[idx]-p) @ Wp1.T + bp1 (store), BN1 partials (3 ch, pad 8)
// ===========================================================================
template <typename T>
__device__ __forceinline__ void pr1_impl(
    const T* __restrict__ p, const int* __restrict__ idx,
    const T* __restrict__ Wp1, const T* __restrict__ bp1,
    float* __restrict__ pr1, float* __restrict__ P1, float (*red)[16])
{
    float W[3][3], B[3];
#pragma unroll
    for (int a = 0; a < 3; ++a) {
        B[a] = cvt<T>(bp1[a]);
#pragma unroll
        for (int d = 0; d < 3; ++d) W[a][d] = cvt<T>(Wp1[a * 3 + d]);
    }
    const int t = threadIdx.x;
    const int base = blockIdx.x * PPB;
    float s[3] = {0.f, 0.f, 0.f}, ss[3] = {0.f, 0.f, 0.f};
    for (int it = 0; it < PPB; it += 256) {
        const int pid = base + it + t;
        const int i = pid >> 3;
        const int nj = idx[pid];
        const float d0 = cvt<T>(p[nj * 3 + 0]) - cvt<T>(p[i * 3 + 0]);
        const float d1 = cvt<T>(p[nj * 3 + 1]) - cvt<T>(p[i * 3 + 1]);
        const float d2 = cvt<T>(p[nj * 3 + 2]) - cvt<T>(p[i * 3 + 2]);
#pragma unroll
        for (int a = 0; a < 3; ++a) {
            const float r = W[a][0] * d0 + W[a][1] * d1 + W[a][2] * d2 + B[a];
            pr1[(size_t)pid * 3 + a] = r;
            s[a] += r; ss[a] += r * r;
        }
    }
#pragma unroll
    for (int o = 32; o > 0; o >>= 1) {
#pragma unroll
        for (int a = 0; a < 3; ++a) { s[a] += __shfl_down(s[a], o); ss[a] += __shfl_down(ss[a], o); }
    }
    const int wid = t >> 6, lane = t & 63;
    if (lane == 0) {
#pragma unroll
        for (int u = 0; u < 16; ++u) red[wid][u] = 0.f;
#pragma unroll
        for (int a = 0; a < 3; ++a) { red[wid][a] = s[a]; red[wid][8 + a] = ss[a]; }
    }
    __syncthreads();
    if (t < 16) P1[blockIdx.x * 16 + t] = red[0][t] + red[1][t] + red[2][t] + red[3][t];
}

__global__ __launch_bounds__(256) void k_pr1(
    const void* p, const int* __restrict__ idx, const void* Wp1, const void* bp1,
    float* pr1, float* P1, const int* __restrict__ flag)
{
    __shared__ float red[4][16];
    if (flag[0] == 0)
        pr1_impl<bf16>((const bf16*)p, idx, (const bf16*)Wp1, (const bf16*)bp1, pr1, P1, red);
    else
        pr1_impl<float>((const float*)p, idx, (const float*)Wp1, (const float*)bp1, pr1, P1, red);
}

// ===========================================================================
// Finalize: reduce GSTAT partial rows (2*NP cols) -> coef a/c. 1024 threads.
// ===========================================================================
template <typename T, int NC_, int NP_>
__device__ __forceinline__ void fin_impl(
    const float* __restrict__ P, const int nblocks,
    const T* __restrict__ g, const T* __restrict__ b,
    float* __restrict__ A, float* __restrict__ Cc, float* red)
{
    constexpr int COLS = 2 * NP_;
    constexpr int GRP  = 1024 / COLS;
    const int t = threadIdx.x;
    const int c = t % COLS;
    const int gi = t / COLS;
    float acc = 0.f;
    for (int r = gi; r < nblocks; r += GRP) acc += P[r * COLS + c];
    red[t] = acc;
    __syncthreads();
#pragma unroll
    for (int s = GRP >> 1; s > 0; s >>= 1) {
        if (gi < s) red[t] += red[t + s * COLS];
        __syncthreads();
    }
    if (t < NC_) {
        const float m = red[t] * INVCNT;
        const float var = red[NP_ + t] * INVCNT - m * m;
        const float a = cvt<T>(g[t]) * rsqrtf(var + EPSV);
        A[t] = a;
        Cc[t] = cvt<T>(b[t]) - a * m;
    }
}

template <int NC_, int NP_>
__global__ __launch_bounds__(1024) void k_fin(
    const float* P, const int nblocks, const void* g, const void* b,
    float* A, float* Cc, const int* __restrict__ flag)
{
    __shared__ float red[1024];
    if (flag[0] == 0)
        fin_impl<bf16, NC_, NP_>(P, nblocks, (const bf16*)g, (const bf16*)b, A, Cc, red);
    else
        fin_impl<float, NC_, NP_>(P, nblocks, (const float*)g, (const float*)b, A, Cc, red);
}

// ===========================================================================
// K4: BN2 partials over w_pre = k[idx] - q + relu(bn1(pr1)) @ Wp2.T + bp2
// c = t&31 channel-parallel; 4-way ILP batches.
// ===========================================================================
template <typename T>
__device__ __forceinline__ void bn2_impl(
    const int* __restrict__ idx, const float* __restrict__ pr1,
    const float* __restrict__ q, const float* __restrict__ k,
    const T* __restrict__ Wp2, const T* __restrict__ bp2,
    const float* __restrict__ coef, float* __restrict__ P2, float (*red)[64])
{
    const int t = threadIdx.x;
    const int c = t & 31;
    const int sub = t >> 5;
    const float a10 = coef[0], a11 = coef[1], a12 = coef[2];
    const float c10 = coef[8], c11 = coef[9], c12 = coef[10];
    const float w0 = cvt<T>(Wp2[c * 3 + 0]), w1 = cvt<T>(Wp2[c * 3 + 1]), w2 = cvt<T>(Wp2[c * 3 + 2]);
    const float bb = cvt<T>(bp2[c]);
    float s = 0.f, ss = 0.f;
    const int base = blockIdx.x * PPB;
    for (int it = 0; it < PPB; it += 32) {
        int pids[4], njs[4];
#pragma unroll
        for (int u = 0; u < 4; ++u) pids[u] = base + it + u * 8 + sub;
#pragma unroll
        for (int u = 0; u < 4; ++u) njs[u] = idx[pids[u]];
        float h[4][3];
#pragma unroll
        for (int u = 0; u < 4; ++u) {
            h[u][0] = fmaxf(a10 * pr1[(size_t)pids[u] * 3 + 0] + c10, 0.f);
            h[u][1] = fmaxf(a11 * pr1[(size_t)pids[u] * 3 + 1] + c11, 0.f);
            h[u][2] = fmaxf(a12 * pr1[(size_t)pids[u] * 3 + 2] + c12, 0.f);
        }
        float kv[4], qv[4];
#pragma unroll
        for (int u = 0; u < 4; ++u) {
            kv[u] = k[(size_t)njs[u] * 32 + c];
            qv[u] = q[(size_t)(pids[u] >> 3) * 32 + c];
        }
#pragma unroll
        for (int u = 0; u < 4; ++u) {
            const float pr2 = w0 * h[u][0] + w1 * h[u][1] + w2 * h[u][2] + bb;
            const float wp = kv[u] - qv[u] + pr2;
            s += wp; ss += wp * wp;
        }
    }
    s += __shfl_down(s, 32); ss += __shfl_down(ss, 32);
    const int wid = t >> 6, lane = t & 63;
    if (lane < 32) { red[wid][lane] = s; red[wid][32 + lane] = ss; }
    __syncthreads();
    if (t < 64) P2[blockIdx.x * 64 + t] = red[0][t] + red[1][t] + red[2][t] + red[3][t];
}

__global__ __launch_bounds__(256) void k_bn2stat(
    const int* __restrict__ idx, const float* pr1, const float* q, const float* k,
    const void* Wp2, const void* bp2, const float* coef, float* P2,
    const int* __restrict__ flag)
{
    __shared__ float red[4][64];
    if (flag[0] == 0)
        bn2_impl<bf16>(idx, pr1, q, k, (const bf16*)Wp2, (const bf16*)bp2, coef, P2, red);
    else
        bn2_impl<float>(idx, pr1, q, k, (const float*)Wp2, (const float*)bp2, coef, P2, red);
}

// ===========================================================================
// K6: w1 = relu(bn2(w_pre)) @ Ww1.T + bww1 (store), BN3 partials (4 ch)
// Thread-per-pair. R6 post-mortem: full-row register arrays (16x float4)
// spilled to scratch under the VGPR cap (FETCH 152MB->1.4GB, WRITE 33->678MB).
// Fix: 4 chunks of 8 channels, 2x float4 live + next chunk prefetched;
// bounded live set + __launch_bounds__(256,4) for ~4x R5 occupancy.
// ===========================================================================
struct ShW1 {
    float Wp2c[32][3];
    float bp2[32];
    float W1[4][32];
    float b1[4];
    float a2[32];
    float c2[32];
    float red[4][8];
};

template <typename T>
__device__ __forceinline__ void w1_impl(
    const int* __restrict__ idx, const float* __restrict__ pr1,
    const float* __restrict__ q, const float* __restrict__ k,
    const T* __restrict__ Wp2, const T* __restrict__ bp2,
    const T* __restrict__ Ww1, const T* __restrict__ bww1,
    const float* __restrict__ coef, float* __restrict__ w1out, float* __restrict__ P3,
    ShW1* sh)
{
    const int t = threadIdx.x;
    if (t < 32) {
        sh->Wp2c[t][0] = cvt<T>(Wp2[t * 3 + 0]);
        sh->Wp2c[t][1] = cvt<T>(Wp2[t * 3 + 1]);
        sh->Wp2c[t][2] = cvt<T>(Wp2[t * 3 + 2]);
        sh->bp2[t] = cvt<T>(bp2[t]);
        sh->a2[t] = coef[16 + t];
        sh->c2[t] = coef[48 + t];
    }
    if (t < 4) sh->b1[t] = cvt<T>(bww1[t]);
    if (t < 128) sh->W1[t >> 5][t & 31] = cvt<T>(Ww1[t]);
    __syncthreads();
    const float a10 = coef[0], a11 = coef[1], a12 = coef[2];
    const float c10 = coef[8], c11 = coef[9], c12 = coef[10];
    float s[4] = {0.f, 0.f, 0.f, 0.f}, ss[4] = {0.f, 0.f, 0.f, 0.f};
    const int base = blockIdx.x * PPB;
    for (int it = 0; it < PPB; it += 256) {
        const int pid = base + it + t;
        const int i = pid >> 3;
        const int nj = idx[pid];
        const float4* k4 = (const float4*)(k + (size_t)nj * 32);
        const float4* q4 = (const float4*)(q + (size_t)i * 32);
        // chunk 0 in flight
        float4 ka = k4[0], kb = k4[1], qa = q4[0], qb = q4[1];
        const float h0 = fmaxf(a10 * pr1[(size_t)pid * 3 + 0] + c10, 0.f);
        const float h1 = fmaxf(a11 * pr1[(size_t)pid * 3 + 1] + c11, 0.f);
        const float h2 = fmaxf(a12 * pr1[(size_t)pid * 3 + 2] + c12, 0.f);
        float acc0 = sh->b1[0], acc1 = sh->b1[1], acc2 = sh->b1[2], acc3 = sh->b1[3];
#pragma unroll
        for (int u = 0; u < 4; ++u) {
            float4 ka2, kb2, qa2, qb2;
            if (u < 3) {                       // prefetch next chunk
                ka2 = k4[2 * u + 2]; kb2 = k4[2 * u + 3];
                qa2 = q4[2 * u + 2]; qb2 = q4[2 * u + 3];
            }
            const float kd[8] = {ka.x - qa.x, ka.y - qa.y, ka.z - qa.z, ka.w - qa.w,
                                 kb.x - qb.x, kb.y - qb.y, kb.z - qb.z, kb.w - qb.w};
#pragma unroll
            for (int e = 0; e < 8; ++e) {
                const int cc = u * 8 + e;
                const float pr2 = sh->Wp2c[cc][0] * h0 + sh->Wp2c[cc][1] * h1
                                + sh->Wp2c[cc][2] * h2 + sh->bp2[cc];
                const float wp = kd[e] + pr2;
                const float hh = fmaxf(sh->a2[cc] * wp + sh->c2[cc], 0.f);
                acc0 += sh->W1[0][cc] * hh;
                acc1 += sh->W1[1][cc] * hh;
                acc2 += sh->W1[2][cc] * hh;
                acc3 += sh->W1[3][cc] * hh;
            }
            if (u < 3) { ka = ka2; kb = kb2; qa = qa2; qb = qb2; }
        }
        float* wr = w1out + (size_t)pid * 4;
        wr[0] = acc0; wr[1] = acc1; wr[2] = acc2; wr[3] = acc3;
        s[0] += acc0; ss[0] += acc0 * acc0;
        s[1] += acc1; ss[1] += acc1 * acc1;
        s[2] += acc2; ss[2] += acc2 * acc2;
        s[3] += acc3; ss[3] += acc3 * acc3;
    }
#pragma unroll
    for (int o = 32; o > 0; o >>= 1) {
#pragma unroll
        for (int u = 0; u < 4; ++u) { s[u] += __shfl_down(s[u], o); ss[u] += __shfl_down(ss[u], o); }
    }
    const int wid = t >> 6, lane = t & 63;
    if (lane == 0) {
#pragma unroll
        for (int u = 0; u < 4; ++u) { sh->red[wid][u] = s[u]; sh->red[wid][4 + u] = ss[u]; }
    }
    __syncthreads();
    if (t < 8) P3[blockIdx.x * 8 + t] = sh->red[0][t] + sh->red[1][t] + sh->red[2][t] + sh->red[3][t];
}

__global__ __launch_bounds__(256, 4) void k_w1(
    const int* __restrict__ idx, const float* pr1, const float* q, const float* k,
    const void* Wp2, const void* bp2, const void* Ww1, const void* bww1,
    const float* coef, float* w1out, float* P3, const int* __restrict__ flag)
{
    __shared__ ShW1 sh;
    if (flag[0] == 0)
        w1_impl<bf16>(idx, pr1, q, k, (const bf16*)Wp2, (const bf16*)bp2,
                      (const bf16*)Ww1, (const bf16*)bww1, coef, w1out, P3, &sh);
    else
        w1_impl<float>(idx, pr1, q, k, (const float*)Wp2, (const float*)bp2,
                       (const float*)Ww1, (const float*)bww1, coef, w1out, P3, &sh);
}

// ===========================================================================
// K8: logits = relu(bn3(w1)) @ Ww2.T + bww2; softmax over ns;
//     out[i,c] = sum_j (v[idx]+pr2) * wsoft[j, c&3].  128 points per block.
// ===========================================================================
template <typename T>
__device__ __forceinline__ void out_impl(
    const int* __restrict__ idx, const float* __restrict__ pr1,
    const float* __restrict__ v, const float* __restrict__ w1in,
    const T* __restrict__ Wp2, const T* __restrict__ bp2,
    const T* __restrict__ Ww2, const T* __restrict__ bww2,
    const float* __restrict__ coef, T* __restrict__ out)
{
    const int t = threadIdx.x;
    const int c = t & 31, pi = t >> 5;
    const float a10 = coef[0], a11 = coef[1], a12 = coef[2];
    const float c10 = coef[8], c11 = coef[9], c12 = coef[10];
    const float wA = cvt<T>(Wp2[c * 3 + 0]), wB = cvt<T>(Wp2[c * 3 + 1]), wC = cvt<T>(Wp2[c * 3 + 2]);
    const float bb = cvt<T>(bp2[c]);
    const int tq = c & 3;
    float a3[4], c3[4], W2r[4];
#pragma unroll
    for (int u = 0; u < 4; ++u) {
        a3[u] = coef[80 + u]; c3[u] = coef[88 + u];
        W2r[u] = cvt<T>(Ww2[tq * 4 + u]);
    }
    const float b2r = cvt<T>(bww2[tq]);
    const int base0 = blockIdx.x * 128;
    for (int it = 0; it < 16; ++it) {
        const int i = base0 + it * 8 + pi;
        int njs[8];
#pragma unroll
        for (int j = 0; j < 8; ++j) njs[j] = idx[(size_t)i * 8 + j];
        float vv[8];
#pragma unroll
        for (int j = 0; j < 8; ++j) vv[j] = v[(size_t)njs[j] * 32 + c];
        float lg[8];
#pragma unroll
        for (int j = 0; j < 8; ++j) {
            const float* wr = w1in + ((size_t)i * 8 + j) * 4;
            float l = b2r;
#pragma unroll
            for (int u = 0; u < 4; ++u) l += W2r[u] * fmaxf(a3[u] * wr[u] + c3[u], 0.f);
            lg[j] = l;
        }
        float h[8][3];
#pragma unroll
        for (int j = 0; j < 8; ++j) {
            const size_t pb = ((size_t)i * 8 + j) * 3;
            h[j][0] = fmaxf(a10 * pr1[pb + 0] + c10, 0.f);
            h[j][1] = fmaxf(a11 * pr1[pb + 1] + c11, 0.f);
            h[j][2] = fmaxf(a12 * pr1[pb + 2] + c12, 0.f);
        }
        float m = lg[0];
#pragma unroll
        for (int j = 1; j < 8; ++j) m = fmaxf(m, lg[j]);
        float sum = 0.f;
#pragma unroll
        for (int j = 0; j < 8; ++j) { lg[j] = __expf(lg[j] - m); sum += lg[j]; }
        const float inv = 1.f / sum;
        float acc = 0.f;
#pragma unroll
        for (int j = 0; j < 8; ++j) {
            const float pr2 = wA * h[j][0] + wB * h[j][1] + wC * h[j][2] + bb;
            acc += (vv[j] + pr2) * (lg[j] * inv);
        }
        out[(size_t)i * 32 + c] = f2t<T>(acc);
    }
}

__global__ __launch_bounds__(256, 4) void k_out(
    const int* __restrict__ idx, const float* pr1, const float* v, const float* w1in,
    const void* Wp2, const void* bp2, const void* Ww2, const void* bww2,
    const float* coef, void* out, const int* __restrict__ flag)
{
    if (flag[0] == 0)
        out_impl<bf16>(idx, pr1, v, w1in, (const bf16*)Wp2, (const bf16*)bp2,
                       (const bf16*)Ww2, (const bf16*)bww2, coef, (bf16*)out);
    else
        out_impl<float>(idx, pr1, v, w1in, (const float*)Wp2, (const float*)bp2,
                        (const float*)Ww2, (const float*)bww2, coef, (float*)out);
}

// ---------------------------------------------------------------------------
extern "C" void kernel_launch(void* const* d_in, const int* in_sizes, int n_in,
                              void* d_out, int out_size, void* d_ws, size_t ws_size,
                              hipStream_t stream)
{
    const void* p    = d_in[0];
    const void* x    = d_in[1];
    const int*  idx  = (const int*)d_in[2];
    const void* Wq   = d_in[3];
    const void* bq   = d_in[4];
    const void* Wk   = d_in[5];
    const void* bk   = d_in[6];
    const void* Wv   = d_in[7];
    const void* bv   = d_in[8];
    const void* Wp1  = d_in[9];
    const void* bp1  = d_in[10];
    const void* gp   = d_in[11];
    const void* bp   = d_in[12];
    const void* Wp2  = d_in[13];
    const void* bp2  = d_in[14];
    const void* gw1  = d_in[15];
    const void* bw1  = d_in[16];
    const void* Ww1  = d_in[17];
    const void* bww1 = d_in[18];
    const void* gw2  = d_in[19];
    const void* bw2  = d_in[20];
    const void* Ww2  = d_in[21];
    const void* bww2 = d_in[22];

    float* ws = (float*)d_ws;
    int* flag = (int*)ws;                     // ws[0]
    // ws layout: [0] flag (+pad), [16..112) coef, [128..) partials, big arrays after 262144
    float* coef = ws + 16;                    // 96 floats
    float* P1   = ws + 128;                   // GSTAT*16
    float* P2   = P1 + GSTAT * 16;            // GSTAT*64
    float* P3   = P2 + GSTAT * 64;            // GSTAT*8
    float* q    = ws + 262144;                // NPTS*32
    float* k    = q  + (size_t)NPTS * 32;     // NPTS*32
    float* v    = k  + (size_t)NPTS * 32;     // NPTS*32
    float* pr1  = v  + (size_t)NPTS * 32;     // NPAIR*3
    float* w1   = pr1 + (size_t)NPAIR * 3;    // NPAIR*4   (total ~160 MB)

    k_detect<<<1, 64, 0, stream>>>((const unsigned int*)x, flag);
    k_qkv<<<2048, 256, 0, stream>>>(x, Wq, bq, Wk, bk, Wv, bv, q, k, v, flag);
    k_pr1<<<GSTAT, 256, 0, stream>>>(p, idx, Wp1, bp1, pr1, P1, flag);
    k_fin<3, 8><<<1, 1024, 0, stream>>>(P1, GSTAT, gp, bp, coef + 0, coef + 8, flag);
    k_bn2stat<<<GSTAT, 256, 0, stream>>>(idx, pr1, q, k, Wp2, bp2, coef, P2, flag);
    k_fin<32, 32><<<1, 1024, 0, stream>>>(P2, GSTAT, gw1, bw1, coef + 16, coef + 48, flag);
    k_w1<<<GSTAT, 256, 0, stream>>>(idx, pr1, q, k, Wp2, bp2, Ww1, bww1, coef, w1, P3, flag);
    k_fin<4, 4><<<1, 1024, 0, stream>>>(P3, GSTAT, gw2, bw2, coef + 80, coef + 88, flag);
    k_out<<<2048, 256, 0, stream>>>(idx, pr1, v, w1, Wp2, bp2, Ww2, bww2, coef, d_out, flag);
}

// Round 8
// 665.529 us; speedup vs baseline: 1.8380x; 1.8291x over previous
//
#include <hip/hip_runtime.h>
#include <hip/hip_bf16.h>

// Problem constants (from reference): N=262144, NS=8, C=32, S=8 -> C/S=4
#define NPTS   262144
#define NSAMP  8
#define NPAIR  (NPTS * NSAMP)           // 2097152
#define EPSV   1e-5f
#define INVCNT (1.0f / (float)NPAIR)
#define GSTAT  2048                      // pair-kernel grid: 8 blocks/CU
#define PPB    (NPAIR / GSTAT)           // 1024 pairs per block
#define PTSB   (PPB / 8)                 // 128 points per block

typedef __hip_bfloat16 bf16;

template <typename T> __device__ __forceinline__ float cvt(T v);
template <> __device__ __forceinline__ float cvt<float>(float v) { return v; }
template <> __device__ __forceinline__ float cvt<bf16>(bf16 v) { return __bfloat162float(v); }

template <typename T> __device__ __forceinline__ T f2t(float v);
template <> __device__ __forceinline__ float f2t<float>(float v) { return v; }
template <> __device__ __forceinline__ bf16  f2t<bf16>(float v)  { return __float2bfloat16(v); }

// ---------------------------------------------------------------------------
// Detector: bf16 inputs (flag=0) vs fp32 inputs (flag=1).
// ---------------------------------------------------------------------------
__global__ void k_detect(const unsigned int* __restrict__ xw, int* __restrict__ flag)
{
    if (threadIdx.x == 0 && blockIdx.x == 0) {
        int cnt = 0;
        for (int i = 0; i < 256; ++i) {
            const unsigned int w = xw[i];
            const unsigned int e = (w >> 7) & 0xFF;   // exponent of low bf16
            if (e >= 110 && e <= 132) ++cnt;
        }
        flag[0] = (cnt >= 128) ? 0 : 1;
    }
}

// ===========================================================================
// K1: q,k,v = x @ W.T + b (fp32 out). thread=(point-in-chunk, c), 128 pts/blk
// ===========================================================================
template <typename T>
__device__ __forceinline__ void qkv_impl(
    const T* __restrict__ x,
    const T* __restrict__ Wq, const T* __restrict__ bq,
    const T* __restrict__ Wk, const T* __restrict__ bk,
    const T* __restrict__ Wv, const T* __restrict__ bv,
    float* __restrict__ q, float* __restrict__ k, float* __restrict__ v,
    float (*Wt)[32][32], float (*xs)[32])
{
    const int t = threadIdx.x;
    for (int e = t; e < 1024; e += 256) {
        const int c = e >> 5, j = e & 31;
        Wt[0][j][c] = cvt<T>(Wq[e]);
        Wt[1][j][c] = cvt<T>(Wk[e]);
        Wt[2][j][c] = cvt<T>(Wv[e]);
    }
    __syncthreads();
    const int c = t & 31, pi = t >> 5;
    const float bqv = cvt<T>(bq[c]), bkv = cvt<T>(bk[c]), bvv = cvt<T>(bv[c]);
    const int base0 = blockIdx.x * 128;
    for (int it = 0; it < 16; ++it) {
        const int base = base0 + it * 8;
        __syncthreads();
        xs[t >> 5][t & 31] = cvt<T>(x[(size_t)base * 32 + t]);
        __syncthreads();
        float aq = bqv, ak = bkv, av = bvv;
#pragma unroll
        for (int j = 0; j < 32; ++j) {
            const float xv = xs[pi][j];
            aq += Wt[0][j][c] * xv;
            ak += Wt[1][j][c] * xv;
            av += Wt[2][j][c] * xv;
        }
        const size_t o = (size_t)(base + pi) * 32 + c;
        q[o] = aq; k[o] = ak; v[o] = av;
    }
}

__global__ __launch_bounds__(256) void k_qkv(
    const void* x, const void* Wq, const void* bq, const void* Wk, const void* bk,
    const void* Wv, const void* bv,
    float* q, float* k, float* v, const int* __restrict__ flag)
{
    __shared__ float Wt[3][32][32];
    __shared__ float xs[8][32];
    if (flag[0] == 0)
        qkv_impl<bf16>((const bf16*)x, (const bf16*)Wq, (const bf16*)bq, (const bf16*)Wk,
                       (const bf16*)bk, (const bf16*)Wv, (const bf16*)bv, q, k, v, Wt, xs);
    else
        qkv_impl<float>((const float*)x, (const float*)Wq, (const float*)bq, (const float*)Wk,
                        (const float*)bk, (const float*)Wv, (const float*)bv, q, k, v, Wt, xs);
}

// ===========================================================================
// K2: pr1 = (p[idx]-p) @ Wp1.T + bp1 (store), BN1 partials (3 ch, pad 8)
// ===========================================================================
template <typename T>
__device__ __forceinline__ void pr1_impl(
    const T* __restrict__ p, const int* __restrict__ idx,
    const T* __restrict__ Wp1, const T* __restrict__ bp1,
    float* __restrict__ pr1, float* __restrict__ P1, float (*red)[16])
{
    float W[3][3], B[3];
#pragma unroll
    for (int a = 0; a < 3; ++a) {
        B[a] = cvt<T>(bp1[a]);
#pragma unroll
        for (int d = 0; d < 3; ++d) W[a][d] = cvt<T>(Wp1[a * 3 + d]);
    }
    const int t = threadIdx.x;
    const int base = blockIdx.x * PPB;
    float s[3] = {0.f, 0.f, 0.f}, ss[3] = {0.f, 0.f, 0.f};
    for (int it = 0; it < PPB; it += 256) {
        const int pid = base + it + t;
        const int i = pid >> 3;
        const int nj = idx[pid];
        const float d0 = cvt<T>(p[nj * 3 + 0]) - cvt<T>(p[i * 3 + 0]);
        const float d1 = cvt<T>(p[nj * 3 + 1]) - cvt<T>(p[i * 3 + 1]);
        const float d2 = cvt<T>(p[nj * 3 + 2]) - cvt<T>(p[i * 3 + 2]);
#pragma unroll
        for (int a = 0; a < 3; ++a) {
            const float r = W[a][0] * d0 + W[a][1] * d1 + W[a][2] * d2 + B[a];
            pr1[(size_t)pid * 3 + a] = r;
            s[a] += r; ss[a] += r * r;
        }
    }
#pragma unroll
    for (int o = 32; o > 0; o >>= 1) {
#pragma unroll
        for (int a = 0; a < 3; ++a) { s[a] += __shfl_down(s[a], o); ss[a] += __shfl_down(ss[a], o); }
    }
    const int wid = t >> 6, lane = t & 63;
    if (lane == 0) {
#pragma unroll
        for (int u = 0; u < 16; ++u) red[wid][u] = 0.f;
#pragma unroll
        for (int a = 0; a < 3; ++a) { red[wid][a] = s[a]; red[wid][8 + a] = ss[a]; }
    }
    __syncthreads();
    if (t < 16) P1[blockIdx.x * 16 + t] = red[0][t] + red[1][t] + red[2][t] + red[3][t];
}

__global__ __launch_bounds__(256) void k_pr1(
    const void* p, const int* __restrict__ idx, const void* Wp1, const void* bp1,
    float* pr1, float* P1, const int* __restrict__ flag)
{
    __shared__ float red[4][16];
    if (flag[0] == 0)
        pr1_impl<bf16>((const bf16*)p, idx, (const bf16*)Wp1, (const bf16*)bp1, pr1, P1, red);
    else
        pr1_impl<float>((const float*)p, idx, (const float*)Wp1, (const float*)bp1, pr1, P1, red);
}

// ===========================================================================
// Finalize: reduce GSTAT partial rows (2*NP cols) -> coef a/c. 1024 threads.
// ===========================================================================
template <typename T, int NC_, int NP_>
__device__ __forceinline__ void fin_impl(
    const float* __restrict__ P, const int nblocks,
    const T* __restrict__ g, const T* __restrict__ b,
    float* __restrict__ A, float* __restrict__ Cc, float* red)
{
    constexpr int COLS = 2 * NP_;
    constexpr int GRP  = 1024 / COLS;
    const int t = threadIdx.x;
    const int c = t % COLS;
    const int gi = t / COLS;
    float acc = 0.f;
    for (int r = gi; r < nblocks; r += GRP) acc += P[r * COLS + c];
    red[t] = acc;
    __syncthreads();
#pragma unroll
    for (int s = GRP >> 1; s > 0; s >>= 1) {
        if (gi < s) red[t] += red[t + s * COLS];
        __syncthreads();
    }
    if (t < NC_) {
        const float m = red[t] * INVCNT;
        const float var = red[NP_ + t] * INVCNT - m * m;
        const float a = cvt<T>(g[t]) * rsqrtf(var + EPSV);
        A[t] = a;
        Cc[t] = cvt<T>(b[t]) - a * m;
    }
}

template <int NC_, int NP_>
__global__ __launch_bounds__(1024) void k_fin(
    const float* P, const int nblocks, const void* g, const void* b,
    float* A, float* Cc, const int* __restrict__ flag)
{
    __shared__ float red[1024];
    if (flag[0] == 0)
        fin_impl<bf16, NC_, NP_>(P, nblocks, (const bf16*)g, (const bf16*)b, A, Cc, red);
    else
        fin_impl<float, NC_, NP_>(P, nblocks, (const float*)g, (const float*)b, A, Cc, red);
}

// ===========================================================================
// K4: BN2 partials over w_pre = k[idx] - q + relu(bn1(pr1)) @ Wp2.T + bp2
// c = t&31 channel-parallel; 4-way ILP batches.
// ===========================================================================
template <typename T>
__device__ __forceinline__ void bn2_impl(
    const int* __restrict__ idx, const float* __restrict__ pr1,
    const float* __restrict__ q, const float* __restrict__ k,
    const T* __restrict__ Wp2, const T* __restrict__ bp2,
    const float* __restrict__ coef, float* __restrict__ P2, float (*red)[64])
{
    const int t = threadIdx.x;
    const int c = t & 31;
    const int sub = t >> 5;
    const float a10 = coef[0], a11 = coef[1], a12 = coef[2];
    const float c10 = coef[8], c11 = coef[9], c12 = coef[10];
    const float w0 = cvt<T>(Wp2[c * 3 + 0]), w1 = cvt<T>(Wp2[c * 3 + 1]), w2 = cvt<T>(Wp2[c * 3 + 2]);
    const float bb = cvt<T>(bp2[c]);
    float s = 0.f, ss = 0.f;
    const int base = blockIdx.x * PPB;
    for (int it = 0; it < PPB; it += 32) {
        int pids[4], njs[4];
#pragma unroll
        for (int u = 0; u < 4; ++u) pids[u] = base + it + u * 8 + sub;
#pragma unroll
        for (int u = 0; u < 4; ++u) njs[u] = idx[pids[u]];
        float h[4][3];
#pragma unroll
        for (int u = 0; u < 4; ++u) {
            h[u][0] = fmaxf(a10 * pr1[(size_t)pids[u] * 3 + 0] + c10, 0.f);
            h[u][1] = fmaxf(a11 * pr1[(size_t)pids[u] * 3 + 1] + c11, 0.f);
            h[u][2] = fmaxf(a12 * pr1[(size_t)pids[u] * 3 + 2] + c12, 0.f);
        }
        float kv[4], qv[4];
#pragma unroll
        for (int u = 0; u < 4; ++u) {
            kv[u] = k[(size_t)njs[u] * 32 + c];
            qv[u] = q[(size_t)(pids[u] >> 3) * 32 + c];
        }
#pragma unroll
        for (int u = 0; u < 4; ++u) {
            const float pr2 = w0 * h[u][0] + w1 * h[u][1] + w2 * h[u][2] + bb;
            const float wp = kv[u] - qv[u] + pr2;
            s += wp; ss += wp * wp;
        }
    }
    s += __shfl_down(s, 32); ss += __shfl_down(ss, 32);
    const int wid = t >> 6, lane = t & 63;
    if (lane < 32) { red[wid][lane] = s; red[wid][32 + lane] = ss; }
    __syncthreads();
    if (t < 64) P2[blockIdx.x * 64 + t] = red[0][t] + red[1][t] + red[2][t] + red[3][t];
}

__global__ __launch_bounds__(256) void k_bn2stat(
    const int* __restrict__ idx, const float* pr1, const float* q, const float* k,
    const void* Wp2, const void* bp2, const float* coef, float* P2,
    const int* __restrict__ flag)
{
    __shared__ float red[4][64];
    if (flag[0] == 0)
        bn2_impl<bf16>(idx, pr1, q, k, (const bf16*)Wp2, (const bf16*)bp2, coef, P2, red);
    else
        bn2_impl<float>(idx, pr1, q, k, (const float*)Wp2, (const float*)bp2, coef, P2, red);
}

// ===========================================================================
// K6: w1 = relu(bn2(w_pre)) @ Ww1.T + bww1 (store), BN3 partials (4 ch)
// R7 post-mortem: thread-per-pair with register rows spills regardless of
// chunking (compiler hoists loads; FETCH 1.4GB scratch). Restructured to
// CHANNEL-PARALLEL (like k_bn2stat): lane=(c, sub); one coalesced float per
// lane per k-row; 4-output dot via 5-round __shfl_xor butterfly over the
// 32-lane half-wave. Per-thread live set ~12 scalars -> no spill possible.
// ===========================================================================
template <typename T>
__device__ __forceinline__ void w1_impl(
    const int* __restrict__ idx, const float* __restrict__ pr1,
    const float* __restrict__ q, const float* __restrict__ k,
    const T* __restrict__ Wp2, const T* __restrict__ bp2,
    const T* __restrict__ Ww1, const T* __restrict__ bww1,
    const float* __restrict__ coef, float* __restrict__ w1out, float* __restrict__ P3,
    float (*red)[8])
{
    const int t = threadIdx.x;
    const int c = t & 31;          // channel
    const int sub = t >> 5;        // neighbor slot 0..7
    const float a10 = coef[0], a11 = coef[1], a12 = coef[2];
    const float c10 = coef[8], c11 = coef[9], c12 = coef[10];
    const float w0 = cvt<T>(Wp2[c * 3 + 0]);
    const float w1c = cvt<T>(Wp2[c * 3 + 1]);
    const float w2 = cvt<T>(Wp2[c * 3 + 2]);
    const float bbp = cvt<T>(bp2[c]);
    const float a2c = coef[16 + c], c2c = coef[48 + c];
    const float W1r0 = cvt<T>(Ww1[0 * 32 + c]);
    const float W1r1 = cvt<T>(Ww1[1 * 32 + c]);
    const float W1r2 = cvt<T>(Ww1[2 * 32 + c]);
    const float W1r3 = cvt<T>(Ww1[3 * 32 + c]);
    const float b1c = (c < 4) ? cvt<T>(bww1[c]) : 0.f;
    float sbn = 0.f, ssbn = 0.f;   // BN3 partials, live on lanes c<4
    const int point0 = blockIdx.x * PTSB;
    for (int it = 0; it < PTSB; ++it) {
        const int i = point0 + it;
        const int pid = i * 8 + sub;
        const int nj = idx[pid];
        const float kv = k[(size_t)nj * 32 + c];   // coalesced 128B line per sub
        const float qv = q[(size_t)i * 32 + c];    // same row for whole block
        const float h0 = fmaxf(a10 * pr1[(size_t)pid * 3 + 0] + c10, 0.f);
        const float h1 = fmaxf(a11 * pr1[(size_t)pid * 3 + 1] + c11, 0.f);
        const float h2 = fmaxf(a12 * pr1[(size_t)pid * 3 + 2] + c12, 0.f);
        const float pr2 = w0 * h0 + w1c * h1 + w2 * h2 + bbp;
        const float wp = kv - qv + pr2;
        const float hh = fmaxf(a2c * wp + c2c, 0.f);
        float s0 = W1r0 * hh, s1 = W1r1 * hh, s2 = W1r2 * hh, s3 = W1r3 * hh;
#pragma unroll
        for (int m = 1; m < 32; m <<= 1) {
            s0 += __shfl_xor(s0, m);
            s1 += __shfl_xor(s1, m);
            s2 += __shfl_xor(s2, m);
            s3 += __shfl_xor(s3, m);
        }
        if (c < 4) {
            const float val = (c == 0 ? s0 : c == 1 ? s1 : c == 2 ? s2 : s3) + b1c;
            w1out[(size_t)pid * 4 + c] = val;
            sbn += val; ssbn += val * val;
        }
    }
    // combine subs within wave (lanes 0-3 <- lanes 32-35), then across waves
    sbn += __shfl_down(sbn, 32); ssbn += __shfl_down(ssbn, 32);
    const int wid = t >> 6, lane = t & 63;
    if (lane < 4) { red[wid][lane] = sbn; red[wid][4 + lane] = ssbn; }
    __syncthreads();
    if (t < 8) P3[blockIdx.x * 8 + t] = red[0][t] + red[1][t] + red[2][t] + red[3][t];
}

__global__ __launch_bounds__(256) void k_w1(
    const int* __restrict__ idx, const float* pr1, const float* q, const float* k,
    const void* Wp2, const void* bp2, const void* Ww1, const void* bww1,
    const float* coef, float* w1out, float* P3, const int* __restrict__ flag)
{
    __shared__ float red[4][8];
    if (flag[0] == 0)
        w1_impl<bf16>(idx, pr1, q, k, (const bf16*)Wp2, (const bf16*)bp2,
                      (const bf16*)Ww1, (const bf16*)bww1, coef, w1out, P3, red);
    else
        w1_impl<float>(idx, pr1, q, k, (const float*)Wp2, (const float*)bp2,
                       (const float*)Ww1, (const float*)bww1, coef, w1out, P3, red);
}

// ===========================================================================
// K8: logits = relu(bn3(w1)) @ Ww2.T + bww2; softmax over ns;
//     out[i,c] = sum_j (v[idx]+pr2) * wsoft[j, c&3].  128 points per block.
// ===========================================================================
template <typename T>
__device__ __forceinline__ void out_impl(
    const int* __restrict__ idx, const float* __restrict__ pr1,
    const float* __restrict__ v, const float* __restrict__ w1in,
    const T* __restrict__ Wp2, const T* __restrict__ bp2,
    const T* __restrict__ Ww2, const T* __restrict__ bww2,
    const float* __restrict__ coef, T* __restrict__ out)
{
    const int t = threadIdx.x;
    const int c = t & 31, pi = t >> 5;
    const float a10 = coef[0], a11 = coef[1], a12 = coef[2];
    const float c10 = coef[8], c11 = coef[9], c12 = coef[10];
    const float wA = cvt<T>(Wp2[c * 3 + 0]), wB = cvt<T>(Wp2[c * 3 + 1]), wC = cvt<T>(Wp2[c * 3 + 2]);
    const float bb = cvt<T>(bp2[c]);
    const int tq = c & 3;
    float a3[4], c3[4], W2r[4];
#pragma unroll
    for (int u = 0; u < 4; ++u) {
        a3[u] = coef[80 + u]; c3[u] = coef[88 + u];
        W2r[u] = cvt<T>(Ww2[tq * 4 + u]);
    }
    const float b2r = cvt<T>(bww2[tq]);
    const int base0 = blockIdx.x * 128;
    for (int it = 0; it < 16; ++it) {
        const int i = base0 + it * 8 + pi;
        int njs[8];
#pragma unroll
        for (int j = 0; j < 8; ++j) njs[j] = idx[(size_t)i * 8 + j];
        float vv[8];
#pragma unroll
        for (int j = 0; j < 8; ++j) vv[j] = v[(size_t)njs[j] * 32 + c];
        float lg[8];
#pragma unroll
        for (int j = 0; j < 8; ++j) {
            const float* wr = w1in + ((size_t)i * 8 + j) * 4;
            float l = b2r;
#pragma unroll
            for (int u = 0; u < 4; ++u) l += W2r[u] * fmaxf(a3[u] * wr[u] + c3[u], 0.f);
            lg[j] = l;
        }
        float h[8][3];
#pragma unroll
        for (int j = 0; j < 8; ++j) {
            const size_t pb = ((size_t)i * 8 + j) * 3;
            h[j][0] = fmaxf(a10 * pr1[pb + 0] + c10, 0.f);
            h[j][1] = fmaxf(a11 * pr1[pb + 1] + c11, 0.f);
            h[j][2] = fmaxf(a12 * pr1[pb + 2] + c12, 0.f);
        }
        float m = lg[0];
#pragma unroll
        for (int j = 1; j < 8; ++j) m = fmaxf(m, lg[j]);
        float sum = 0.f;
#pragma unroll
        for (int j = 0; j < 8; ++j) { lg[j] = __expf(lg[j] - m); sum += lg[j]; }
        const float inv = 1.f / sum;
        float acc = 0.f;
#pragma unroll
        for (int j = 0; j < 8; ++j) {
            const float pr2 = wA * h[j][0] + wB * h[j][1] + wC * h[j][2] + bb;
            acc += (vv[j] + pr2) * (lg[j] * inv);
        }
        out[(size_t)i * 32 + c] = f2t<T>(acc);
    }
}

__global__ __launch_bounds__(256, 4) void k_out(
    const int* __restrict__ idx, const float* pr1, const float* v, const float* w1in,
    const void* Wp2, const void* bp2, const void* Ww2, const void* bww2,
    const float* coef, void* out, const int* __restrict__ flag)
{
    if (flag[0] == 0)
        out_impl<bf16>(idx, pr1, v, w1in, (const bf16*)Wp2, (const bf16*)bp2,
                       (const bf16*)Ww2, (const bf16*)bww2, coef, (bf16*)out);
    else
        out_impl<float>(idx, pr1, v, w1in, (const float*)Wp2, (const float*)bp2,
                        (const float*)Ww2, (const float*)bww2, coef, (float*)out);
}

// ---------------------------------------------------------------------------
extern "C" void kernel_launch(void* const* d_in, const int* in_sizes, int n_in,
                              void* d_out, int out_size, void* d_ws, size_t ws_size,
                              hipStream_t stream)
{
    const void* p    = d_in[0];
    const void* x    = d_in[1];
    const int*  idx  = (const int*)d_in[2];
    const void* Wq   = d_in[3];
    const void* bq   = d_in[4];
    const void* Wk   = d_in[5];
    const void* bk   = d_in[6];
    const void* Wv   = d_in[7];
    const void* bv   = d_in[8];
    const void* Wp1  = d_in[9];
    const void* bp1  = d_in[10];
    const void* gp   = d_in[11];
    const void* bp   = d_in[12];
    const void* Wp2  = d_in[13];
    const void* bp2  = d_in[14];
    const void* gw1  = d_in[15];
    const void* bw1  = d_in[16];
    const void* Ww1  = d_in[17];
    const void* bww1 = d_in[18];
    const void* gw2  = d_in[19];
    const void* bw2  = d_in[20];
    const void* Ww2  = d_in[21];
    const void* bww2 = d_in[22];

    float* ws = (float*)d_ws;
    int* flag = (int*)ws;                     // ws[0]
    // ws layout: [0] flag (+pad), [16..112) coef, [128..) partials, big arrays after 262144
    float* coef = ws + 16;                    // 96 floats
    float* P1   = ws + 128;                   // GSTAT*16
    float* P2   = P1 + GSTAT * 16;            // GSTAT*64
    float* P3   = P2 + GSTAT * 64;            // GSTAT*8
    float* q    = ws + 262144;                // NPTS*32
    float* k    = q  + (size_t)NPTS * 32;     // NPTS*32
    float* v    = k  + (size_t)NPTS * 32;     // NPTS*32
    float* pr1  = v  + (size_t)NPTS * 32;     // NPAIR*3
    float* w1   = pr1 + (size_t)NPAIR * 3;    // NPAIR*4   (total ~160 MB)

    k_detect<<<1, 64, 0, stream>>>((const unsigned int*)x, flag);
    k_qkv<<<2048, 256, 0, stream>>>(x, Wq, bq, Wk, bk, Wv, bv, q, k, v, flag);
    k_pr1<<<GSTAT, 256, 0, stream>>>(p, idx, Wp1, bp1, pr1, P1, flag);
    k_fin<3, 8><<<1, 1024, 0, stream>>>(P1, GSTAT, gp, bp, coef + 0, coef + 8, flag);
    k_bn2stat<<<GSTAT, 256, 0, stream>>>(idx, pr1, q, k, Wp2, bp2, coef, P2, flag);
    k_fin<32, 32><<<1, 1024, 0, stream>>>(P2, GSTAT, gw1, bw1, coef + 16, coef + 48, flag);
    k_w1<<<GSTAT, 256, 0, stream>>>(idx, pr1, q, k, Wp2, bp2, Ww1, bww1, coef, w1, P3, flag);
    k_fin<4, 4><<<1, 1024, 0, stream>>>(P3, GSTAT, gw2, bw2, coef + 80, coef + 88, flag);
    k_out<<<2048, 256, 0, stream>>>(idx, pr1, v, w1, Wp2, bp2, Ww2, bww2, coef, d_out, flag);
}

// Round 9
// 619.604 us; speedup vs baseline: 1.9743x; 1.0741x over previous
//
#include <hip/hip_runtime.h>
#include <hip/hip_bf16.h>

// Problem constants (from reference): N=262144, NS=8, C=32, S=8 -> C/S=4
#define NPTS   262144
#define NSAMP  8
#define NPAIR  (NPTS * NSAMP)           // 2097152
#define EPSV   1e-5f
#define INVCNT (1.0f / (float)NPAIR)
#define GSTAT  2048                      // pair-kernel grid: 8 blocks/CU
#define PPB    (NPAIR / GSTAT)           // 1024 pairs per block
#define PTSB   (PPB / 8)                 // 128 points per block

typedef __hip_bfloat16 bf16;

template <typename T> __device__ __forceinline__ float cvt(T v);
template <> __device__ __forceinline__ float cvt<float>(float v) { return v; }
template <> __device__ __forceinline__ float cvt<bf16>(bf16 v) { return __bfloat162float(v); }

template <typename T> __device__ __forceinline__ T f2t(float v);
template <> __device__ __forceinline__ float f2t<float>(float v) { return v; }
template <> __device__ __forceinline__ bf16  f2t<bf16>(float v)  { return __float2bfloat16(v); }

// ---------------------------------------------------------------------------
// Detector: bf16 inputs (flag=0) vs fp32 inputs (flag=1).
// ---------------------------------------------------------------------------
__global__ void k_detect(const unsigned int* __restrict__ xw, int* __restrict__ flag)
{
    if (threadIdx.x == 0 && blockIdx.x == 0) {
        int cnt = 0;
        for (int i = 0; i < 256; ++i) {
            const unsigned int w = xw[i];
            const unsigned int e = (w >> 7) & 0xFF;   // exponent of low bf16
            if (e >= 110 && e <= 132) ++cnt;
        }
        flag[0] = (cnt >= 128) ? 0 : 1;
    }
}

// ===========================================================================
// K1: q,k,v = x @ W.T + b (fp32 out). thread=(point-in-chunk, c), 128 pts/blk
// ===========================================================================
template <typename T>
__device__ __forceinline__ void qkv_impl(
    const T* __restrict__ x,
    const T* __restrict__ Wq, const T* __restrict__ bq,
    const T* __restrict__ Wk, const T* __restrict__ bk,
    const T* __restrict__ Wv, const T* __restrict__ bv,
    float* __restrict__ q, float* __restrict__ k, float* __restrict__ v,
    float (*Wt)[32][32], float (*xs)[32])
{
    const int t = threadIdx.x;
    for (int e = t; e < 1024; e += 256) {
        const int c = e >> 5, j = e & 31;
        Wt[0][j][c] = cvt<T>(Wq[e]);
        Wt[1][j][c] = cvt<T>(Wk[e]);
        Wt[2][j][c] = cvt<T>(Wv[e]);
    }
    __syncthreads();
    const int c = t & 31, pi = t >> 5;
    const float bqv = cvt<T>(bq[c]), bkv = cvt<T>(bk[c]), bvv = cvt<T>(bv[c]);
    const int base0 = blockIdx.x * 128;
    for (int it = 0; it < 16; ++it) {
        const int base = base0 + it * 8;
        __syncthreads();
        xs[t >> 5][t & 31] = cvt<T>(x[(size_t)base * 32 + t]);
        __syncthreads();
        float aq = bqv, ak = bkv, av = bvv;
#pragma unroll
        for (int j = 0; j < 32; ++j) {
            const float xv = xs[pi][j];
            aq += Wt[0][j][c] * xv;
            ak += Wt[1][j][c] * xv;
            av += Wt[2][j][c] * xv;
        }
        const size_t o = (size_t)(base + pi) * 32 + c;
        q[o] = aq; k[o] = ak; v[o] = av;
    }
}

__global__ __launch_bounds__(256) void k_qkv(
    const void* x, const void* Wq, const void* bq, const void* Wk, const void* bk,
    const void* Wv, const void* bv,
    float* q, float* k, float* v, const int* __restrict__ flag)
{
    __shared__ float Wt[3][32][32];
    __shared__ float xs[8][32];
    if (flag[0] == 0)
        qkv_impl<bf16>((const bf16*)x, (const bf16*)Wq, (const bf16*)bq, (const bf16*)Wk,
                       (const bf16*)bk, (const bf16*)Wv, (const bf16*)bv, q, k, v, Wt, xs);
    else
        qkv_impl<float>((const float*)x, (const float*)Wq, (const float*)bq, (const float*)Wk,
                        (const float*)bk, (const float*)Wv, (const float*)bv, q, k, v, Wt, xs);
}

// ===========================================================================
// K2: pr1 = (p[idx]-p) @ Wp1.T + bp1 (store), BN1 partials (3 ch, pad 8)
// ===========================================================================
template <typename T>
__device__ __forceinline__ void pr1_impl(
    const T* __restrict__ p, const int* __restrict__ idx,
    const T* __restrict__ Wp1, const T* __restrict__ bp1,
    float* __restrict__ pr1, float* __restrict__ P1, float (*red)[16])
{
    float W[3][3], B[3];
#pragma unroll
    for (int a = 0; a < 3; ++a) {
        B[a] = cvt<T>(bp1[a]);
#pragma unroll
        for (int d = 0; d < 3; ++d) W[a][d] = cvt<T>(Wp1[a * 3 + d]);
    }
    const int t = threadIdx.x;
    const int base = blockIdx.x * PPB;
    float s[3] = {0.f, 0.f, 0.f}, ss[3] = {0.f, 0.f, 0.f};
    for (int it = 0; it < PPB; it += 256) {
        const int pid = base + it + t;
        const int i = pid >> 3;
        const int nj = idx[pid];
        const float d0 = cvt<T>(p[nj * 3 + 0]) - cvt<T>(p[i * 3 + 0]);
        const float d1 = cvt<T>(p[nj * 3 + 1]) - cvt<T>(p[i * 3 + 1]);
        const float d2 = cvt<T>(p[nj * 3 + 2]) - cvt<T>(p[i * 3 + 2]);
#pragma unroll
        for (int a = 0; a < 3; ++a) {
            const float r = W[a][0] * d0 + W[a][1] * d1 + W[a][2] * d2 + B[a];
            pr1[(size_t)pid * 3 + a] = r;
            s[a] += r; ss[a] += r * r;
        }
    }
#pragma unroll
    for (int o = 32; o > 0; o >>= 1) {
#pragma unroll
        for (int a = 0; a < 3; ++a) { s[a] += __shfl_down(s[a], o); ss[a] += __shfl_down(ss[a], o); }
    }
    const int wid = t >> 6, lane = t & 63;
    if (lane == 0) {
#pragma unroll
        for (int u = 0; u < 16; ++u) red[wid][u] = 0.f;
#pragma unroll
        for (int a = 0; a < 3; ++a) { red[wid][a] = s[a]; red[wid][8 + a] = ss[a]; }
    }
    __syncthreads();
    if (t < 16) P1[blockIdx.x * 16 + t] = red[0][t] + red[1][t] + red[2][t] + red[3][t];
}

__global__ __launch_bounds__(256) void k_pr1(
    const void* p, const int* __restrict__ idx, const void* Wp1, const void* bp1,
    float* pr1, float* P1, const int* __restrict__ flag)
{
    __shared__ float red[4][16];
    if (flag[0] == 0)
        pr1_impl<bf16>((const bf16*)p, idx, (const bf16*)Wp1, (const bf16*)bp1, pr1, P1, red);
    else
        pr1_impl<float>((const float*)p, idx, (const float*)Wp1, (const float*)bp1, pr1, P1, red);
}

// ===========================================================================
// Finalize: reduce GSTAT partial rows (2*NP cols) -> coef a/c. 1024 threads.
// ===========================================================================
template <typename T, int NC_, int NP_>
__device__ __forceinline__ void fin_impl(
    const float* __restrict__ P, const int nblocks,
    const T* __restrict__ g, const T* __restrict__ b,
    float* __restrict__ A, float* __restrict__ Cc, float* red)
{
    constexpr int COLS = 2 * NP_;
    constexpr int GRP  = 1024 / COLS;
    const int t = threadIdx.x;
    const int c = t % COLS;
    const int gi = t / COLS;
    float acc = 0.f;
    for (int r = gi; r < nblocks; r += GRP) acc += P[r * COLS + c];
    red[t] = acc;
    __syncthreads();
#pragma unroll
    for (int s = GRP >> 1; s > 0; s >>= 1) {
        if (gi < s) red[t] += red[t + s * COLS];
        __syncthreads();
    }
    if (t < NC_) {
        const float m = red[t] * INVCNT;
        const float var = red[NP_ + t] * INVCNT - m * m;
        const float a = cvt<T>(g[t]) * rsqrtf(var + EPSV);
        A[t] = a;
        Cc[t] = cvt<T>(b[t]) - a * m;
    }
}

template <int NC_, int NP_>
__global__ __launch_bounds__(1024) void k_fin(
    const float* P, const int nblocks, const void* g, const void* b,
    float* A, float* Cc, const int* __restrict__ flag)
{
    __shared__ float red[1024];
    if (flag[0] == 0)
        fin_impl<bf16, NC_, NP_>(P, nblocks, (const bf16*)g, (const bf16*)b, A, Cc, red);
    else
        fin_impl<float, NC_, NP_>(P, nblocks, (const float*)g, (const float*)b, A, Cc, red);
}

// ===========================================================================
// K4: BN2 partials over w_pre = k[idx] - q + relu(bn1(pr1)) @ Wp2.T + bp2
// c = t&31 channel-parallel; 4-way ILP batches.
// ===========================================================================
template <typename T>
__device__ __forceinline__ void bn2_impl(
    const int* __restrict__ idx, const float* __restrict__ pr1,
    const float* __restrict__ q, const float* __restrict__ k,
    const T* __restrict__ Wp2, const T* __restrict__ bp2,
    const float* __restrict__ coef, float* __restrict__ P2, float (*red)[64])
{
    const int t = threadIdx.x;
    const int c = t & 31;
    const int sub = t >> 5;
    const float a10 = coef[0], a11 = coef[1], a12 = coef[2];
    const float c10 = coef[8], c11 = coef[9], c12 = coef[10];
    const float w0 = cvt<T>(Wp2[c * 3 + 0]), w1 = cvt<T>(Wp2[c * 3 + 1]), w2 = cvt<T>(Wp2[c * 3 + 2]);
    const float bb = cvt<T>(bp2[c]);
    float s = 0.f, ss = 0.f;
    const int base = blockIdx.x * PPB;
    for (int it = 0; it < PPB; it += 32) {
        int pids[4], njs[4];
#pragma unroll
        for (int u = 0; u < 4; ++u) pids[u] = base + it + u * 8 + sub;
#pragma unroll
        for (int u = 0; u < 4; ++u) njs[u] = idx[pids[u]];
        float h[4][3];
#pragma unroll
        for (int u = 0; u < 4; ++u) {
            h[u][0] = fmaxf(a10 * pr1[(size_t)pids[u] * 3 + 0] + c10, 0.f);
            h[u][1] = fmaxf(a11 * pr1[(size_t)pids[u] * 3 + 1] + c11, 0.f);
            h[u][2] = fmaxf(a12 * pr1[(size_t)pids[u] * 3 + 2] + c12, 0.f);
        }
        float kv[4], qv[4];
#pragma unroll
        for (int u = 0; u < 4; ++u) {
            kv[u] = k[(size_t)njs[u] * 32 + c];
            qv[u] = q[(size_t)(pids[u] >> 3) * 32 + c];
        }
#pragma unroll
        for (int u = 0; u < 4; ++u) {
            const float pr2 = w0 * h[u][0] + w1 * h[u][1] + w2 * h[u][2] + bb;
            const float wp = kv[u] - qv[u] + pr2;
            s += wp; ss += wp * wp;
        }
    }
    s += __shfl_down(s, 32); ss += __shfl_down(ss, 32);
    const int wid = t >> 6, lane = t & 63;
    if (lane < 32) { red[wid][lane] = s; red[wid][32 + lane] = ss; }
    __syncthreads();
    if (t < 64) P2[blockIdx.x * 64 + t] = red[0][t] + red[1][t] + red[2][t] + red[3][t];
}

__global__ __launch_bounds__(256) void k_bn2stat(
    const int* __restrict__ idx, const float* pr1, const float* q, const float* k,
    const void* Wp2, const void* bp2, const float* coef, float* P2,
    const int* __restrict__ flag)
{
    __shared__ float red[4][64];
    if (flag[0] == 0)
        bn2_impl<bf16>(idx, pr1, q, k, (const bf16*)Wp2, (const bf16*)bp2, coef, P2, red);
    else
        bn2_impl<float>(idx, pr1, q, k, (const float*)Wp2, (const float*)bp2, coef, P2, red);
}

// ===========================================================================
// K6: w1 = relu(bn2(w_pre)) @ Ww1.T + bww1 (store), BN3 partials (4 ch)
// R8 post-mortem: 20 wave-wide shuffles/point saturated the LDS pipe (~270us).
// New lane map: pair gets 32 lanes = (u = lane&3 output) x (cg = lane>>2
// channel-quad). Each lane owns 4 channels: one float4 of k/q + folded BN2
// constants in ~24 regs (loaded once, no LDS in loop, no spill). Reduction:
// 3 shfl_xor rounds (xor 4/8/16 over cg). cg==0 lanes store 16B/pair; the 8
// pair-slots of a point form one contiguous 128B store line.
// ===========================================================================
template <typename T>
__device__ __forceinline__ void w1_impl(
    const int* __restrict__ idx, const float* __restrict__ pr1,
    const float* __restrict__ q, const float* __restrict__ k,
    const T* __restrict__ Wp2, const T* __restrict__ bp2,
    const T* __restrict__ Ww1, const T* __restrict__ bww1,
    const float* __restrict__ coef, float* __restrict__ w1out, float* __restrict__ P3,
    float (*red)[8])
{
    const int t = threadIdx.x;
    const int group = t >> 5;      // pair-slot 0..7 (neighbor j)
    const int lane32 = t & 31;
    const int u  = lane32 & 3;     // output channel 0..3
    const int cg = lane32 >> 2;    // channel-quad 0..7
    const float a10 = coef[0], a11 = coef[1], a12 = coef[2];
    const float c10 = coef[8], c11 = coef[9], c12 = coef[10];
    // folded per-channel constants for the 4 owned channels cc = 4*cg+e:
    // arg = A*(k-q) + B0*h0 + B1*h1 + B2*h2 + Bb ; hh = relu(arg)
    float A[4], B0[4], B1[4], B2[4], Bb[4], W1u[4];
#pragma unroll
    for (int e = 0; e < 4; ++e) {
        const int cc = 4 * cg + e;
        const float a2 = coef[16 + cc];
        A[e]  = a2;
        B0[e] = a2 * cvt<T>(Wp2[cc * 3 + 0]);
        B1[e] = a2 * cvt<T>(Wp2[cc * 3 + 1]);
        B2[e] = a2 * cvt<T>(Wp2[cc * 3 + 2]);
        Bb[e] = a2 * cvt<T>(bp2[cc]) + coef[48 + cc];
        W1u[e] = cvt<T>(Ww1[u * 32 + cc]);
    }
    const float b1u = cvt<T>(bww1[u]);
    float sbn = 0.f, ssbn = 0.f;   // BN3 partials (live on cg==0 lanes)
    const int point0 = blockIdx.x * PTSB;
    for (int it = 0; it < PTSB; ++it) {
        const int i = point0 + it;
        const int pid = i * 8 + group;
        const int nj = idx[pid];
        const float4 k4 = *(const float4*)(k + (size_t)nj * 32 + 4 * cg);
        const float4 q4 = *(const float4*)(q + (size_t)i * 32 + 4 * cg);
        const float h0 = fmaxf(a10 * pr1[(size_t)pid * 3 + 0] + c10, 0.f);
        const float h1 = fmaxf(a11 * pr1[(size_t)pid * 3 + 1] + c11, 0.f);
        const float h2 = fmaxf(a12 * pr1[(size_t)pid * 3 + 2] + c12, 0.f);
        const float kd[4] = {k4.x - q4.x, k4.y - q4.y, k4.z - q4.z, k4.w - q4.w};
        float su = 0.f;
#pragma unroll
        for (int e = 0; e < 4; ++e) {
            const float arg = A[e] * kd[e] + B0[e] * h0 + B1[e] * h1 + B2[e] * h2 + Bb[e];
            su += W1u[e] * fmaxf(arg, 0.f);
        }
        su += __shfl_xor(su, 4);
        su += __shfl_xor(su, 8);
        su += __shfl_xor(su, 16);
        if (cg == 0) {
            const float val = su + b1u;
            w1out[(size_t)pid * 4 + u] = val;
            sbn += val; ssbn += val * val;
        }
    }
    // combine the two 32-halves of each wave, then across waves via LDS
    sbn += __shfl_down(sbn, 32); ssbn += __shfl_down(ssbn, 32);
    const int wid = t >> 6, lane = t & 63;
    if (lane < 4) { red[wid][lane] = sbn; red[wid][4 + lane] = ssbn; }
    __syncthreads();
    if (t < 8) P3[blockIdx.x * 8 + t] = red[0][t] + red[1][t] + red[2][t] + red[3][t];
}

__global__ __launch_bounds__(256) void k_w1(
    const int* __restrict__ idx, const float* pr1, const float* q, const float* k,
    const void* Wp2, const void* bp2, const void* Ww1, const void* bww1,
    const float* coef, float* w1out, float* P3, const int* __restrict__ flag)
{
    __shared__ float red[4][8];
    if (flag[0] == 0)
        w1_impl<bf16>(idx, pr1, q, k, (const bf16*)Wp2, (const bf16*)bp2,
                      (const bf16*)Ww1, (const bf16*)bww1, coef, w1out, P3, red);
    else
        w1_impl<float>(idx, pr1, q, k, (const float*)Wp2, (const float*)bp2,
                       (const float*)Ww1, (const float*)bww1, coef, w1out, P3, red);
}

// ===========================================================================
// K8: logits = relu(bn3(w1)) @ Ww2.T + bww2; softmax over ns;
//     out[i,c] = sum_j (v[idx]+pr2) * wsoft[j, c&3].  128 points per block.
// ===========================================================================
template <typename T>
__device__ __forceinline__ void out_impl(
    const int* __restrict__ idx, const float* __restrict__ pr1,
    const float* __restrict__ v, const float* __restrict__ w1in,
    const T* __restrict__ Wp2, const T* __restrict__ bp2,
    const T* __restrict__ Ww2, const T* __restrict__ bww2,
    const float* __restrict__ coef, T* __restrict__ out)
{
    const int t = threadIdx.x;
    const int c = t & 31, pi = t >> 5;
    const float a10 = coef[0], a11 = coef[1], a12 = coef[2];
    const float c10 = coef[8], c11 = coef[9], c12 = coef[10];
    const float wA = cvt<T>(Wp2[c * 3 + 0]), wB = cvt<T>(Wp2[c * 3 + 1]), wC = cvt<T>(Wp2[c * 3 + 2]);
    const float bb = cvt<T>(bp2[c]);
    const int tq = c & 3;
    float a3[4], c3[4], W2r[4];
#pragma unroll
    for (int u = 0; u < 4; ++u) {
        a3[u] = coef[80 + u]; c3[u] = coef[88 + u];
        W2r[u] = cvt<T>(Ww2[tq * 4 + u]);
    }
    const float b2r = cvt<T>(bww2[tq]);
    const int base0 = blockIdx.x * 128;
    for (int it = 0; it < 16; ++it) {
        const int i = base0 + it * 8 + pi;
        int njs[8];
#pragma unroll
        for (int j = 0; j < 8; ++j) njs[j] = idx[(size_t)i * 8 + j];
        float vv[8];
#pragma unroll
        for (int j = 0; j < 8; ++j) vv[j] = v[(size_t)njs[j] * 32 + c];
        float lg[8];
#pragma unroll
        for (int j = 0; j < 8; ++j) {
            const float* wr = w1in + ((size_t)i * 8 + j) * 4;
            float l = b2r;
#pragma unroll
            for (int u = 0; u < 4; ++u) l += W2r[u] * fmaxf(a3[u] * wr[u] + c3[u], 0.f);
            lg[j] = l;
        }
        float h[8][3];
#pragma unroll
        for (int j = 0; j < 8; ++j) {
            const size_t pb = ((size_t)i * 8 + j) * 3;
            h[j][0] = fmaxf(a10 * pr1[pb + 0] + c10, 0.f);
            h[j][1] = fmaxf(a11 * pr1[pb + 1] + c11, 0.f);
            h[j][2] = fmaxf(a12 * pr1[pb + 2] + c12, 0.f);
        }
        float m = lg[0];
#pragma unroll
        for (int j = 1; j < 8; ++j) m = fmaxf(m, lg[j]);
        float sum = 0.f;
#pragma unroll
        for (int j = 0; j < 8; ++j) { lg[j] = __expf(lg[j] - m); sum += lg[j]; }
        const float inv = 1.f / sum;
        float acc = 0.f;
#pragma unroll
        for (int j = 0; j < 8; ++j) {
            const float pr2 = wA * h[j][0] + wB * h[j][1] + wC * h[j][2] + bb;
            acc += (vv[j] + pr2) * (lg[j] * inv);
        }
        out[(size_t)i * 32 + c] = f2t<T>(acc);
    }
}

__global__ __launch_bounds__(256, 4) void k_out(
    const int* __restrict__ idx, const float* pr1, const float* v, const float* w1in,
    const void* Wp2, const void* bp2, const void* Ww2, const void* bww2,
    const float* coef, void* out, const int* __restrict__ flag)
{
    if (flag[0] == 0)
        out_impl<bf16>(idx, pr1, v, w1in, (const bf16*)Wp2, (const bf16*)bp2,
                       (const bf16*)Ww2, (const bf16*)bww2, coef, (bf16*)out);
    else
        out_impl<float>(idx, pr1, v, w1in, (const float*)Wp2, (const float*)bp2,
                        (const float*)Ww2, (const float*)bww2, coef, (float*)out);
}

// ---------------------------------------------------------------------------
extern "C" void kernel_launch(void* const* d_in, const int* in_sizes, int n_in,
                              void* d_out, int out_size, void* d_ws, size_t ws_size,
                              hipStream_t stream)
{
    const void* p    = d_in[0];
    const void* x    = d_in[1];
    const int*  idx  = (const int*)d_in[2];
    const void* Wq   = d_in[3];
    const void* bq   = d_in[4];
    const void* Wk   = d_in[5];
    const void* bk   = d_in[6];
    const void* Wv   = d_in[7];
    const void* bv   = d_in[8];
    const void* Wp1  = d_in[9];
    const void* bp1  = d_in[10];
    const void* gp   = d_in[11];
    const void* bp   = d_in[12];
    const void* Wp2  = d_in[13];
    const void* bp2  = d_in[14];
    const void* gw1  = d_in[15];
    const void* bw1  = d_in[16];
    const void* Ww1  = d_in[17];
    const void* bww1 = d_in[18];
    const void* gw2  = d_in[19];
    const void* bw2  = d_in[20];
    const void* Ww2  = d_in[21];
    const void* bww2 = d_in[22];

    float* ws = (float*)d_ws;
    int* flag = (int*)ws;                     // ws[0]
    // ws layout: [0] flag (+pad), [16..112) coef, [128..) partials, big arrays after 262144
    float* coef = ws + 16;                    // 96 floats
    float* P1   = ws + 128;                   // GSTAT*16
    float* P2   = P1 + GSTAT * 16;            // GSTAT*64
    float* P3   = P2 + GSTAT * 64;            // GSTAT*8
    float* q    = ws + 262144;                // NPTS*32
    float* k    = q  + (size_t)NPTS * 32;     // NPTS*32
    float* v    = k  + (size_t)NPTS * 32;     // NPTS*32
    float* pr1  = v  + (size_t)NPTS * 32;     // NPAIR*3
    float* w1   = pr1 + (size_t)NPAIR * 3;    // NPAIR*4   (total ~160 MB)

    k_detect<<<1, 64, 0, stream>>>((const unsigned int*)x, flag);
    k_qkv<<<2048, 256, 0, stream>>>(x, Wq, bq, Wk, bk, Wv, bv, q, k, v, flag);
    k_pr1<<<GSTAT, 256, 0, stream>>>(p, idx, Wp1, bp1, pr1, P1, flag);
    k_fin<3, 8><<<1, 1024, 0, stream>>>(P1, GSTAT, gp, bp, coef + 0, coef + 8, flag);
    k_bn2stat<<<GSTAT, 256, 0, stream>>>(idx, pr1, q, k, Wp2, bp2, coef, P2, flag);
    k_fin<32, 32><<<1, 1024, 0, stream>>>(P2, GSTAT, gw1, bw1, coef + 16, coef + 48, flag);
    k_w1<<<GSTAT, 256, 0, stream>>>(idx, pr1, q, k, Wp2, bp2, Ww1, bww1, coef, w1, P3, flag);
    k_fin<4, 4><<<1, 1024, 0, stream>>>(P3, GSTAT, gw2, bw2, coef + 80, coef + 88, flag);
    k_out<<<2048, 256, 0, stream>>>(idx, pr1, v, w1, Wp2, bp2, Ww2, bww2, coef, d_out, flag);
}